// Round 6
// baseline (253.485 us; speedup 1.0000x reference)
//
#include <hip/hip_runtime.h>
#include <hip/hip_bf16.h>

#define N_NODES 10000
#define N_EDGES 100000
#define D 248
#define DP 256      // padded D (K/N padding for MFMA tiles)
#define HDIM 512
#define NNZ 2480
#define LN_EPS 1e-5f

typedef __attribute__((ext_vector_type(8))) short bf16x8_t;  // 8 bf16 = 4 VGPRs
typedef __attribute__((ext_vector_type(4))) float f32x4_t;   // MFMA accum

__device__ __forceinline__ float bf2f(unsigned short u) {
  unsigned int x = ((unsigned int)u) << 16;
  return __builtin_bit_cast(float, x);
}
__device__ __forceinline__ unsigned short f2bf(float f) {
  return __builtin_bit_cast(unsigned short, __float2bfloat16(f));
}

// ---------------------------------------------------------------------------
// Fused prep: weight casts + deg zero + triple CSR (features cast ELIMINATED
// via linearity: gather now sums raw fp32 features).
//   [0, DP)            cast W_msg (D,D)   -> WmB (DP,DP)
//   [DP, DP+HDIM)      cast W1 (H,D)      -> W1B (H,DP)
//   [DP+HDIM, 1024)    cast W2 (D,H)      -> W2B (DP,H)
//   [1024, 1064)       deg[i] = 0
//   1064               CSR of triples by K (packed int2 {J<<16|I, C})
// ---------------------------------------------------------------------------
#define WCAST_BLOCKS (DP + HDIM + DP)   // 1024
#define ZERO_BLOCKS 40
#define PREP_BLOCKS (WCAST_BLOCKS + ZERO_BLOCKS + 1)

__device__ __forceinline__ void cast_row(const float* src, __hip_bfloat16* dst,
                                         int r, int sr, int sc, int dc) {
  for (int c = threadIdx.x; c < dc; c += 256) {
    float v = (r < sr && c < sc) ? src[(size_t)r * sc + c] : 0.f;
    dst[(size_t)r * dc + c] = __float2bfloat16(v);
  }
}

__global__ __launch_bounds__(256) void prep_kernel(
    const float* __restrict__ W_msg, const float* __restrict__ W1,
    const float* __restrict__ W2,
    __hip_bfloat16* __restrict__ WmB, __hip_bfloat16* __restrict__ W1B,
    __hip_bfloat16* __restrict__ W2B, int* __restrict__ deg,
    const int* __restrict__ Iv, const int* __restrict__ Jv,
    const int* __restrict__ Kv, const float* __restrict__ Cv,
    int* __restrict__ rsK, int2* __restrict__ trip) {
  const int b = blockIdx.x;
  if (b < DP) {
    cast_row(W_msg, WmB, b, D, D, DP);
  } else if (b < DP + HDIM) {
    cast_row(W1, W1B, b - DP, HDIM, D, DP);
  } else if (b < WCAST_BLOCKS) {
    cast_row(W2, W2B, b - DP - HDIM, D, HDIM, HDIM);
  } else if (b < WCAST_BLOCKS + ZERO_BLOCKS) {
    int i = (b - WCAST_BLOCKS) * 256 + threadIdx.x;
    if (i < N_NODES) deg[i] = 0;
  } else {
    __shared__ int cnt[D];
    __shared__ int off[D];
    const int tid = threadIdx.x;
    for (int k = tid; k < D; k += 256) cnt[k] = 0;
    __syncthreads();
    for (int t = tid; t < NNZ; t += 256) atomicAdd(&cnt[Kv[t]], 1);
    __syncthreads();
    if (tid == 0) {
      int run = 0;
      for (int k = 0; k < D; k++) { off[k] = run; rsK[k] = run; run += cnt[k]; }
      rsK[D] = run;
    }
    __syncthreads();
    for (int t = tid; t < NNZ; t += 256) {
      int pos = atomicAdd(&off[Kv[t]], 1);
      trip[pos] = make_int2((Jv[t] << 16) | Iv[t], __float_as_int(Cv[t]));
    }
  }
}

// ---------------------------------------------------------------------------
// Edge CSR-by-target: histogram -> scan -> placement
// ---------------------------------------------------------------------------
__global__ __launch_bounds__(256) void hist_tgt(
    const int* __restrict__ ei, int* __restrict__ deg) {
  int e = blockIdx.x * 256 + threadIdx.x;
  if (e < N_EDGES) atomicAdd(&deg[ei[N_EDGES + e]], 1);
}

__global__ __launch_bounds__(256) void scan_deg(
    const int* __restrict__ deg, int* __restrict__ rs, int* __restrict__ woff) {
  __shared__ int part[256];
  const int t = threadIdx.x;
  const int base = t * 40;  // 256*40 = 10240 >= 10000
  int sum = 0;
  for (int i = 0; i < 40; i++) {
    int idx = base + i;
    if (idx < N_NODES) sum += deg[idx];
  }
  part[t] = sum;
  __syncthreads();
  if (t == 0) {
    int run = 0;
    for (int i = 0; i < 256; i++) { int tmp = part[i]; part[i] = run; run += tmp; }
    rs[N_NODES] = run;
  }
  __syncthreads();
  int run = part[t];
  for (int i = 0; i < 40; i++) {
    int idx = base + i;
    if (idx < N_NODES) { rs[idx] = run; woff[idx] = run; run += deg[idx]; }
  }
}

__global__ __launch_bounds__(256) void place_edges(
    const int* __restrict__ ei, int* __restrict__ woff, int* __restrict__ esrc) {
  int e = blockIdx.x * 256 + threadIdx.x;
  if (e < N_EDGES) {
    int pos = atomicAdd(&woff[ei[N_EDGES + e]], 1);
    esrc[pos] = ei[e];
  }
}

// ---------------------------------------------------------------------------
// Gather raw features (linearity: projection moved AFTER aggregation):
//   G[n] = sum_{e: tgt=n} features[src(e)], bf16 out (N,DP)
// Wave per node, NO LDS, NO barrier; 8-deep edge ILP; float4 row loads.
// ---------------------------------------------------------------------------
__global__ __launch_bounds__(256) void gather_G(
    const float* __restrict__ F, const int* __restrict__ rs,
    const int* __restrict__ esrc, unsigned short* __restrict__ G) {
  const int tid = threadIdx.x;
  const int wv = tid >> 6;
  const int lane = tid & 63;
  const int n = blockIdx.x * 4 + wv;  // grid 2500, exact

  const int beg = rs[n];
  const int deg = rs[n + 1] - beg;
  int eid = (lane < deg) ? esrc[beg + lane] : 0;

  float4 a = make_float4(0.f, 0.f, 0.f, 0.f);
  const float* Fl = F + (size_t)lane * 4;  // col offset within row (992B rows, 16B aligned)
  const int degc = (deg < 64) ? deg : 64;
  int j = 0;
  for (; j + 8 <= degc; j += 8) {
    int s0 = __shfl(eid, j + 0), s1 = __shfl(eid, j + 1);
    int s2 = __shfl(eid, j + 2), s3 = __shfl(eid, j + 3);
    int s4 = __shfl(eid, j + 4), s5 = __shfl(eid, j + 5);
    int s6 = __shfl(eid, j + 6), s7 = __shfl(eid, j + 7);
    if (lane < 62) {
      float4 v0 = *(const float4*)(Fl + (size_t)s0 * D);
      float4 v1 = *(const float4*)(Fl + (size_t)s1 * D);
      float4 v2 = *(const float4*)(Fl + (size_t)s2 * D);
      float4 v3 = *(const float4*)(Fl + (size_t)s3 * D);
      float4 v4 = *(const float4*)(Fl + (size_t)s4 * D);
      float4 v5 = *(const float4*)(Fl + (size_t)s5 * D);
      float4 v6 = *(const float4*)(Fl + (size_t)s6 * D);
      float4 v7 = *(const float4*)(Fl + (size_t)s7 * D);
      a.x += ((v0.x + v1.x) + (v2.x + v3.x)) + ((v4.x + v5.x) + (v6.x + v7.x));
      a.y += ((v0.y + v1.y) + (v2.y + v3.y)) + ((v4.y + v5.y) + (v6.y + v7.y));
      a.z += ((v0.z + v1.z) + (v2.z + v3.z)) + ((v4.z + v5.z) + (v6.z + v7.z));
      a.w += ((v0.w + v1.w) + (v2.w + v3.w)) + ((v4.w + v5.w) + (v6.w + v7.w));
    }
  }
  for (; j < deg; j++) {
    int s = (j < 64) ? __shfl(eid, j) : esrc[beg + j];
    if (lane < 62) {
      float4 v = *(const float4*)(Fl + (size_t)s * D);
      a.x += v.x; a.y += v.y; a.z += v.z; a.w += v.w;
    }
  }
  // lanes 62,63 have a == 0 -> they naturally zero the pad cols 248..255
  ushort4 o;
  o.x = f2bf(a.x); o.y = f2bf(a.y); o.z = f2bf(a.z); o.w = f2bf(a.w);
  *(ushort4*)(G + (size_t)n * DP + lane * 4) = o;
}

// ---------------------------------------------------------------------------
// bf16 GEMM-NT via MFMA 16x16x32: C = A @ B^T (+bias)(+silu)
// EPI: 0 = bf16 out; 1 = +bias +silu, bf16 out; 2 = +bias(n<D), f32 out;
//      3 = plain f32 out.
// Tile 128x64x64, 4 waves 2x2, XOR-swizzled LDS.
// ---------------------------------------------------------------------------
template <int EPI>
__global__ __launch_bounds__(256) void gemm_bf16(
    const unsigned short* __restrict__ A, const unsigned short* __restrict__ B,
    const float* __restrict__ bias, void* __restrict__ Cout,
    int M, int Nn, int K, int lda, int ldb, int ldc) {
  constexpr int BM = 128;
  __shared__ unsigned short As[BM * 64];  // 16 KB
  __shared__ unsigned short Bs[64 * 64];  // 8 KB
  const int tid = threadIdx.x;
  const int wave = tid >> 6;
  const int lane = tid & 63;
  const int wm = wave >> 1;
  const int wn = wave & 1;
  const int ml = lane & 15;
  const int q = lane >> 4;
  const int m0 = blockIdx.y * BM;
  const int n0 = blockIdx.x * 64;

  f32x4_t acc[4][2];
#pragma unroll
  for (int i = 0; i < 4; i++)
#pragma unroll
    for (int j = 0; j < 2; j++) acc[i][j] = (f32x4_t)0.f;

  for (int k0 = 0; k0 < K; k0 += 64) {
#pragma unroll
    for (int i = 0; i < 4; i++) {
      int gid = tid + i * 256;
      int r = gid >> 3, g = gid & 7;
      int gr = m0 + r;
      uint4 v = make_uint4(0u, 0u, 0u, 0u);
      if (gr < M) v = *(const uint4*)(A + (size_t)gr * lda + k0 + g * 8);
      *(uint4*)(As + r * 64 + ((g ^ (r & 7)) * 8)) = v;
    }
#pragma unroll
    for (int i = 0; i < 2; i++) {
      int gid = tid + i * 256;
      int r = gid >> 3, g = gid & 7;
      uint4 v = *(const uint4*)(B + (size_t)(n0 + r) * ldb + k0 + g * 8);
      *(uint4*)(Bs + r * 64 + ((g ^ (r & 7)) * 8)) = v;
    }
    __syncthreads();
#pragma unroll
    for (int kk = 0; kk < 2; kk++) {
      bf16x8_t a[4], b[2];
#pragma unroll
      for (int im = 0; im < 4; im++) {
        int row = wm * 64 + im * 16 + ml;
        int g = kk * 4 + q;
        a[im] = *(const bf16x8_t*)(As + row * 64 + ((g ^ (row & 7)) * 8));
      }
#pragma unroll
      for (int jn = 0; jn < 2; jn++) {
        int row = wn * 32 + jn * 16 + ml;
        int g = kk * 4 + q;
        b[jn] = *(const bf16x8_t*)(Bs + row * 64 + ((g ^ (row & 7)) * 8));
      }
#pragma unroll
      for (int im = 0; im < 4; im++)
#pragma unroll
        for (int jn = 0; jn < 2; jn++)
          acc[im][jn] = __builtin_amdgcn_mfma_f32_16x16x32_bf16(
              a[im], b[jn], acc[im][jn], 0, 0, 0);
    }
    __syncthreads();
  }

  // D[m][n]: n = lane&15, m = quad*4 + reg  [verified m89/m91]
#pragma unroll
  for (int im = 0; im < 4; im++) {
#pragma unroll
    for (int jn = 0; jn < 2; jn++) {
      int gn = n0 + wn * 32 + jn * 16 + ml;
#pragma unroll
      for (int reg = 0; reg < 4; reg++) {
        int gm = m0 + wm * 64 + im * 16 + q * 4 + reg;
        if (gm >= M) continue;
        float v = acc[im][jn][reg];
        if (EPI == 1) {
          v += bias[gn];
          v = v / (1.f + __expf(-v));
          ((__hip_bfloat16*)Cout)[(size_t)gm * ldc + gn] = __float2bfloat16(v);
        } else if (EPI == 2) {
          v += (gn < D) ? bias[gn] : 0.f;
          ((float*)Cout)[(size_t)gm * ldc + gn] = v;
        } else if (EPI == 3) {
          ((float*)Cout)[(size_t)gm * ldc + gn] = v;
        } else {
          ((__hip_bfloat16*)Cout)[(size_t)gm * ldc + gn] = __float2bfloat16(v);
        }
      }
    }
  }
}

// ---------------------------------------------------------------------------
// Per-node bracket (S and F staged in LDS; wave-per-node, 4/block):
//   agg[n][k] = sum_{t in rowK(k)} C_t * S[n][I_t] * F[n][J_t]
// ---------------------------------------------------------------------------
__global__ __launch_bounds__(256) void bracket_kernel(
    const float* __restrict__ S, const float* __restrict__ F,
    const int* __restrict__ rsK, const int2* __restrict__ trip,
    __hip_bfloat16* __restrict__ agg) {
  __shared__ float sS[4][DP];
  __shared__ float sF[4][DP];
  const int tid = threadIdx.x;
  const int wv = tid >> 6;
  const int lane = tid & 63;
  const int n = blockIdx.x * 4 + wv;

  ((float4*)sS[wv])[lane] = ((const float4*)(S + (size_t)n * DP))[lane];
  if (lane < 62) ((float4*)sF[wv])[lane] = ((const float4*)(F + (size_t)n * D))[lane];
  __syncthreads();

  const float* Sr = sS[wv];
  const float* Fr = sF[wv];
#pragma unroll
  for (int kk = 0; kk < 4; kk++) {
    int k = lane + kk * 64;
    float a = 0.f;
    if (k < D) {
      const int b = rsK[k], e = rsK[k + 1];
      for (int t = b; t < e; t++) {
        int2 tr = trip[t];
        a += __int_as_float(tr.y) * Sr[tr.x & 0xFFFF] * Fr[tr.x >> 16];
      }
    }
    agg[(size_t)n * DP + k] = __float2bfloat16(a);  // k in [D,DP) -> 0 pad
  }
}

// ---------------------------------------------------------------------------
// Residual + LayerNorm (h2 has DP stride)
// ---------------------------------------------------------------------------
__global__ __launch_bounds__(256) void ln_kernel(
    const float* __restrict__ x0, const float* __restrict__ h2,
    const float* __restrict__ gamma, const float* __restrict__ beta,
    float* __restrict__ out) {
  const int n = blockIdx.x;
  const int tid = threadIdx.x;
  __shared__ float red[256];
  float x = 0.f;
  if (tid < D) x = x0[(size_t)n * D + tid] + h2[(size_t)n * DP + tid];
  red[tid] = (tid < D) ? x : 0.f;
  __syncthreads();
  for (int s = 128; s > 0; s >>= 1) {
    if (tid < s) red[tid] += red[tid + s];
    __syncthreads();
  }
  const float mu = red[0] / (float)D;
  __syncthreads();
  const float xc = (tid < D) ? (x - mu) : 0.f;
  red[tid] = xc * xc;
  __syncthreads();
  for (int s = 128; s > 0; s >>= 1) {
    if (tid < s) red[tid] += red[tid + s];
    __syncthreads();
  }
  const float var = red[0] / (float)D;
  const float rstd = rsqrtf(var + LN_EPS);
  if (tid < D) out[(size_t)n * D + tid] = xc * rstd * gamma[tid] + beta[tid];
}

// ---------------------------------------------------------------------------
extern "C" void kernel_launch(void* const* d_in, const int* in_sizes, int n_in,
                              void* d_out, int out_size, void* d_ws, size_t ws_size,
                              hipStream_t stream) {
  const float* features = (const float*)d_in[0];
  const int*   ei       = (const int*)d_in[1];
  const float* W_msg    = (const float*)d_in[2];
  const float* W1       = (const float*)d_in[3];
  const float* b1       = (const float*)d_in[4];
  const float* W2       = (const float*)d_in[5];
  const float* b2       = (const float*)d_in[6];
  const float* gamma    = (const float*)d_in[7];
  const float* beta     = (const float*)d_in[8];
  const int*   Iv       = (const int*)d_in[9];
  const int*   Jv       = (const int*)d_in[10];
  const int*   Kv       = (const int*)d_in[11];
  const float* Cv       = (const float*)d_in[12];
  float* out = (float*)d_out;

  char* cur = (char*)d_ws;
  auto alloc = [&](size_t bytes) {
    char* p = cur;
    cur += (bytes + 255) & ~(size_t)255;
    return p;
  };
  // lifetimes: G dead after GEMM1; S dead after bracket (H2 reuses S's region);
  // aggB dead after GEMM2.
  __hip_bfloat16* WmB  = (__hip_bfloat16*)alloc((size_t)DP * DP * 2);
  __hip_bfloat16* W1B  = (__hip_bfloat16*)alloc((size_t)HDIM * DP * 2);
  __hip_bfloat16* W2B  = (__hip_bfloat16*)alloc((size_t)DP * HDIM * 2);
  unsigned short* G    = (unsigned short*)alloc((size_t)N_NODES * DP * 2);   // 5.12 MB
  float*          S    = (float*)alloc((size_t)N_NODES * DP * 4);            // 10.24 MB
  __hip_bfloat16* aggB = (__hip_bfloat16*)alloc((size_t)N_NODES * DP * 2);   // 5.12 MB
  unsigned short* H1B  = (unsigned short*)alloc((size_t)N_NODES * HDIM * 2); // 10.24 MB
  float*          H2   = S;  // alias: S dead once bracket has run
  int*  rsK  = (int*)alloc((D + 1) * 4);
  int2* trip = (int2*)alloc(NNZ * 8);
  int*  deg  = (int*)alloc(N_NODES * 4);
  int*  rs   = (int*)alloc((N_NODES + 1) * 4);
  int*  woff = (int*)alloc(N_NODES * 4);
  int*  esrc = (int*)alloc(N_EDGES * 4);

  dim3 blk(256);

  // 1) prep: weight casts + deg zero + triple CSR
  prep_kernel<<<PREP_BLOCKS, blk, 0, stream>>>(
      W_msg, W1, W2, WmB, W1B, W2B, deg, Iv, Jv, Kv, Cv, rsK, trip);
  // 2) edge CSR by target
  hist_tgt<<<(N_EDGES + 255) / 256, blk, 0, stream>>>(ei, deg);
  scan_deg<<<1, blk, 0, stream>>>(deg, rs, woff);
  place_edges<<<(N_EDGES + 255) / 256, blk, 0, stream>>>(ei, woff, esrc);
  // 3) G[n] = sum features[src]  (raw fp32 gather, barrier-free)
  gather_G<<<N_NODES / 4, blk, 0, stream>>>(features, rs, esrc, G);
  // 4) S = G @ Wm^T  (f32 out)
  gemm_bf16<3><<<dim3(DP / 64, (N_NODES + 127) / 128), blk, 0, stream>>>(
      G, (const unsigned short*)WmB, nullptr, S, N_NODES, DP, DP, DP, DP, DP);
  // 5) agg = bracket(S, features)
  bracket_kernel<<<N_NODES / 4, blk, 0, stream>>>(S, features, rsK, trip, aggB);
  // 6) H1 = silu(agg @ W1^T + b1)
  gemm_bf16<1><<<dim3(HDIM / 64, (N_NODES + 127) / 128), blk, 0, stream>>>(
      (const unsigned short*)aggB, (const unsigned short*)W1B, b1, H1B,
      N_NODES, HDIM, DP, DP, DP, HDIM);
  // 7) H2 = H1 @ W2^T + b2  (H2 aliases S)
  gemm_bf16<2><<<dim3(DP / 64, (N_NODES + 127) / 128), blk, 0, stream>>>(
      H1B, (const unsigned short*)W2B, b2, H2, N_NODES, DP, HDIM, HDIM, HDIM, DP);
  // 8) out = LN(features + H2)
  ln_kernel<<<N_NODES, blk, 0, stream>>>(features, H2, gamma, beta, out);
}

// Round 7
// 244.797 us; speedup vs baseline: 1.0355x; 1.0355x over previous
//
#include <hip/hip_runtime.h>
#include <hip/hip_bf16.h>

#define N_NODES 10000
#define N_EDGES 100000
#define D 248
#define DP 256      // padded D (K/N padding for MFMA tiles)
#define HDIM 512
#define NNZ 2480
#define LN_EPS 1e-5f

typedef __attribute__((ext_vector_type(8))) short bf16x8_t;  // 8 bf16 = 4 VGPRs
typedef __attribute__((ext_vector_type(4))) float f32x4_t;   // MFMA accum

__device__ __forceinline__ float bf2f(unsigned short u) {
  unsigned int x = ((unsigned int)u) << 16;
  return __builtin_bit_cast(float, x);
}
__device__ __forceinline__ unsigned short f2bf(float f) {
  return __builtin_bit_cast(unsigned short, __float2bfloat16(f));
}
// unpack packed 2xbf16 word: lo = bits<<16, hi = bits&0xFFFF0000
__device__ __forceinline__ float bflo(unsigned int w) {
  return __builtin_bit_cast(float, w << 16);
}
__device__ __forceinline__ float bfhi(unsigned int w) {
  return __builtin_bit_cast(float, w & 0xFFFF0000u);
}

// ---------------------------------------------------------------------------
// Fused prep, decoded by blockIdx.x:
//   [0, N)             cast features (N,D) -> featB (N,DP) bf16
//   [N, N+DP)          cast W_msg  -> WmB (DP,DP)
//   [N+DP, N+DP+H)     cast W1     -> W1B (H,DP)
//   [.., +DP)          cast W2     -> W2B (DP,H)
//   [.., +40)          deg[i] = 0
//   last               CSR of triples by K (packed int2 {J<<16|I, C})
// ---------------------------------------------------------------------------
#define CAST_BLOCKS (N_NODES + DP + HDIM + DP)
#define ZERO_BLOCKS 40
#define PREP_BLOCKS (CAST_BLOCKS + ZERO_BLOCKS + 1)

__device__ __forceinline__ void cast_row(const float* src, __hip_bfloat16* dst,
                                         int r, int sr, int sc, int dc) {
  for (int c = threadIdx.x; c < dc; c += 256) {
    float v = (r < sr && c < sc) ? src[(size_t)r * sc + c] : 0.f;
    dst[(size_t)r * dc + c] = __float2bfloat16(v);
  }
}

__global__ __launch_bounds__(256) void prep_kernel(
    const float* __restrict__ features, const float* __restrict__ W_msg,
    const float* __restrict__ W1, const float* __restrict__ W2,
    __hip_bfloat16* __restrict__ featB, __hip_bfloat16* __restrict__ WmB,
    __hip_bfloat16* __restrict__ W1B, __hip_bfloat16* __restrict__ W2B,
    int* __restrict__ deg,
    const int* __restrict__ Iv, const int* __restrict__ Jv,
    const int* __restrict__ Kv, const float* __restrict__ Cv,
    int* __restrict__ rsK, int2* __restrict__ trip) {
  const int b = blockIdx.x;
  if (b < N_NODES) {
    cast_row(features, featB, b, N_NODES, D, DP);
  } else if (b < N_NODES + DP) {
    cast_row(W_msg, WmB, b - N_NODES, D, D, DP);
  } else if (b < N_NODES + DP + HDIM) {
    cast_row(W1, W1B, b - N_NODES - DP, HDIM, D, DP);
  } else if (b < CAST_BLOCKS) {
    cast_row(W2, W2B, b - N_NODES - DP - HDIM, D, HDIM, HDIM);
  } else if (b < CAST_BLOCKS + ZERO_BLOCKS) {
    int i = (b - CAST_BLOCKS) * 256 + threadIdx.x;
    if (i < N_NODES) deg[i] = 0;
  } else {
    __shared__ int cnt[D];
    __shared__ int off[D];
    const int tid = threadIdx.x;
    for (int k = tid; k < D; k += 256) cnt[k] = 0;
    __syncthreads();
    for (int t = tid; t < NNZ; t += 256) atomicAdd(&cnt[Kv[t]], 1);
    __syncthreads();
    if (tid == 0) {
      int run = 0;
      for (int k = 0; k < D; k++) { off[k] = run; rsK[k] = run; run += cnt[k]; }
      rsK[D] = run;
    }
    __syncthreads();
    for (int t = tid; t < NNZ; t += 256) {
      int pos = atomicAdd(&off[Kv[t]], 1);
      trip[pos] = make_int2((Jv[t] << 16) | Iv[t], __float_as_int(Cv[t]));
    }
  }
}

// ---------------------------------------------------------------------------
// Edge CSR-by-target: histogram -> scan -> placement
// ---------------------------------------------------------------------------
__global__ __launch_bounds__(256) void hist_tgt(
    const int* __restrict__ ei, int* __restrict__ deg) {
  int e = blockIdx.x * 256 + threadIdx.x;
  if (e < N_EDGES) atomicAdd(&deg[ei[N_EDGES + e]], 1);
}

__global__ __launch_bounds__(256) void scan_deg(
    const int* __restrict__ deg, int* __restrict__ rs, int* __restrict__ woff) {
  __shared__ int part[256];
  const int t = threadIdx.x;
  const int base = t * 40;  // 256*40 = 10240 >= 10000
  int sum = 0;
  for (int i = 0; i < 40; i++) {
    int idx = base + i;
    if (idx < N_NODES) sum += deg[idx];
  }
  part[t] = sum;
  __syncthreads();
  if (t == 0) {
    int run = 0;
    for (int i = 0; i < 256; i++) { int tmp = part[i]; part[i] = run; run += tmp; }
    rs[N_NODES] = run;
  }
  __syncthreads();
  int run = part[t];
  for (int i = 0; i < 40; i++) {
    int idx = base + i;
    if (idx < N_NODES) { rs[idx] = run; woff[idx] = run; run += deg[idx]; }
  }
}

__global__ __launch_bounds__(256) void place_edges(
    const int* __restrict__ ei, int* __restrict__ woff, int* __restrict__ esrc) {
  int e = blockIdx.x * 256 + threadIdx.x;
  if (e < N_EDGES) {
    int pos = atomicAdd(&woff[ei[N_EDGES + e]], 1);
    esrc[pos] = ei[e];
  }
}

// ---------------------------------------------------------------------------
// Gather bf16 rows: G[n] = sum_{e: tgt=n} featB[src(e)], bf16 (N,DP) out.
// Wave per node; wave split into two 32-lane halves, each half streams a
// DIFFERENT edge's row with 16B/lane uint4 loads (31 chunks data + 1 pad).
// Halves combined with shfl_xor(32). No LDS, no barrier.
// ---------------------------------------------------------------------------
__global__ __launch_bounds__(256) void gather_G(
    const unsigned short* __restrict__ FB, const int* __restrict__ rs,
    const int* __restrict__ esrc, unsigned short* __restrict__ G) {
  const int tid = threadIdx.x;
  const int wv = tid >> 6;
  const int lane = tid & 63;
  const int half = lane >> 5;   // 0 or 1
  const int c = lane & 31;      // 16B chunk id (c*8 bf16 cols), always in-bounds (DP=256)
  const int n = blockIdx.x * 4 + wv;  // grid 2500, exact

  const int beg = rs[n];
  const int deg = rs[n + 1] - beg;
  int eid = (lane < deg) ? esrc[beg + lane] : 0;  // coalesced preload (deg<=64 typical)

  float a[8] = {0.f, 0.f, 0.f, 0.f, 0.f, 0.f, 0.f, 0.f};
  const unsigned short* FBc = FB + (size_t)c * 8;
  int j = half;
  for (; j + 2 < deg && j < 64; j += 2) {  // pairwise: this half handles j, j+2,...
    // actually step per-half is 2; both halves interleave over edge list
    int s = __shfl(eid, j);
    uint4 u = *(const uint4*)(FBc + (size_t)s * DP);
    a[0] += bflo(u.x); a[1] += bfhi(u.x);
    a[2] += bflo(u.y); a[3] += bfhi(u.y);
    a[4] += bflo(u.z); a[5] += bfhi(u.z);
    a[6] += bflo(u.w); a[7] += bfhi(u.w);
  }
  for (; j < deg; j += 2) {
    int s = (j < 64) ? __shfl(eid, j) : esrc[beg + j];
    uint4 u = *(const uint4*)(FBc + (size_t)s * DP);
    a[0] += bflo(u.x); a[1] += bfhi(u.x);
    a[2] += bflo(u.y); a[3] += bfhi(u.y);
    a[4] += bflo(u.z); a[5] += bfhi(u.z);
    a[6] += bflo(u.w); a[7] += bfhi(u.w);
  }
  // combine the two halves (partner lane differs only in bit 5)
#pragma unroll
  for (int i = 0; i < 8; i++) a[i] += __shfl_xor(a[i], 32);

  if (half == 0) {
    uint4 o;
    o.x = (unsigned)f2bf(a[0]) | ((unsigned)f2bf(a[1]) << 16);
    o.y = (unsigned)f2bf(a[2]) | ((unsigned)f2bf(a[3]) << 16);
    o.z = (unsigned)f2bf(a[4]) | ((unsigned)f2bf(a[5]) << 16);
    o.w = (unsigned)f2bf(a[6]) | ((unsigned)f2bf(a[7]) << 16);
    *(uint4*)(G + (size_t)n * DP + c * 8) = o;  // c=31 writes pad zeros (featB pad=0)
  }
}

// ---------------------------------------------------------------------------
// bf16 GEMM-NT via MFMA 16x16x32: C = A @ B^T (+bias)(+silu)
// EPI: 0 = bf16 out; 1 = +bias +silu, bf16 out; 2 = +bias(n<D), f32 out;
//      3 = plain f32 out.
// Tile 128x64x64, 4 waves 2x2, XOR-swizzled LDS.
// ---------------------------------------------------------------------------
template <int EPI>
__global__ __launch_bounds__(256) void gemm_bf16(
    const unsigned short* __restrict__ A, const unsigned short* __restrict__ B,
    const float* __restrict__ bias, void* __restrict__ Cout,
    int M, int Nn, int K, int lda, int ldb, int ldc) {
  constexpr int BM = 128;
  __shared__ unsigned short As[BM * 64];  // 16 KB
  __shared__ unsigned short Bs[64 * 64];  // 8 KB
  const int tid = threadIdx.x;
  const int wave = tid >> 6;
  const int lane = tid & 63;
  const int wm = wave >> 1;
  const int wn = wave & 1;
  const int ml = lane & 15;
  const int q = lane >> 4;
  const int m0 = blockIdx.y * BM;
  const int n0 = blockIdx.x * 64;

  f32x4_t acc[4][2];
#pragma unroll
  for (int i = 0; i < 4; i++)
#pragma unroll
    for (int j = 0; j < 2; j++) acc[i][j] = (f32x4_t)0.f;

  for (int k0 = 0; k0 < K; k0 += 64) {
#pragma unroll
    for (int i = 0; i < 4; i++) {
      int gid = tid + i * 256;
      int r = gid >> 3, g = gid & 7;
      int gr = m0 + r;
      uint4 v = make_uint4(0u, 0u, 0u, 0u);
      if (gr < M) v = *(const uint4*)(A + (size_t)gr * lda + k0 + g * 8);
      *(uint4*)(As + r * 64 + ((g ^ (r & 7)) * 8)) = v;
    }
#pragma unroll
    for (int i = 0; i < 2; i++) {
      int gid = tid + i * 256;
      int r = gid >> 3, g = gid & 7;
      uint4 v = *(const uint4*)(B + (size_t)(n0 + r) * ldb + k0 + g * 8);
      *(uint4*)(Bs + r * 64 + ((g ^ (r & 7)) * 8)) = v;
    }
    __syncthreads();
#pragma unroll
    for (int kk = 0; kk < 2; kk++) {
      bf16x8_t a[4], b[2];
#pragma unroll
      for (int im = 0; im < 4; im++) {
        int row = wm * 64 + im * 16 + ml;
        int g = kk * 4 + q;
        a[im] = *(const bf16x8_t*)(As + row * 64 + ((g ^ (row & 7)) * 8));
      }
#pragma unroll
      for (int jn = 0; jn < 2; jn++) {
        int row = wn * 32 + jn * 16 + ml;
        int g = kk * 4 + q;
        b[jn] = *(const bf16x8_t*)(Bs + row * 64 + ((g ^ (row & 7)) * 8));
      }
#pragma unroll
      for (int im = 0; im < 4; im++)
#pragma unroll
        for (int jn = 0; jn < 2; jn++)
          acc[im][jn] = __builtin_amdgcn_mfma_f32_16x16x32_bf16(
              a[im], b[jn], acc[im][jn], 0, 0, 0);
    }
    __syncthreads();
  }

  // D[m][n]: n = lane&15, m = quad*4 + reg  [verified m89/m91]
#pragma unroll
  for (int im = 0; im < 4; im++) {
#pragma unroll
    for (int jn = 0; jn < 2; jn++) {
      int gn = n0 + wn * 32 + jn * 16 + ml;
#pragma unroll
      for (int reg = 0; reg < 4; reg++) {
        int gm = m0 + wm * 64 + im * 16 + q * 4 + reg;
        if (gm >= M) continue;
        float v = acc[im][jn][reg];
        if (EPI == 1) {
          v += bias[gn];
          v = v / (1.f + __expf(-v));
          ((__hip_bfloat16*)Cout)[(size_t)gm * ldc + gn] = __float2bfloat16(v);
        } else if (EPI == 2) {
          v += (gn < D) ? bias[gn] : 0.f;
          ((float*)Cout)[(size_t)gm * ldc + gn] = v;
        } else if (EPI == 3) {
          ((float*)Cout)[(size_t)gm * ldc + gn] = v;
        } else {
          ((__hip_bfloat16*)Cout)[(size_t)gm * ldc + gn] = __float2bfloat16(v);
        }
      }
    }
  }
}

// ---------------------------------------------------------------------------
// Per-node bracket (S and F staged in LDS; wave-per-node, 4/block):
//   agg[n][k] = sum_{t in rowK(k)} C_t * S[n][I_t] * F[n][J_t]
// ---------------------------------------------------------------------------
__global__ __launch_bounds__(256) void bracket_kernel(
    const float* __restrict__ S, const float* __restrict__ F,
    const int* __restrict__ rsK, const int2* __restrict__ trip,
    __hip_bfloat16* __restrict__ agg) {
  __shared__ float sS[4][DP];
  __shared__ float sF[4][DP];
  const int tid = threadIdx.x;
  const int wv = tid >> 6;
  const int lane = tid & 63;
  const int n = blockIdx.x * 4 + wv;

  ((float4*)sS[wv])[lane] = ((const float4*)(S + (size_t)n * DP))[lane];
  if (lane < 62) ((float4*)sF[wv])[lane] = ((const float4*)(F + (size_t)n * D))[lane];
  __syncthreads();

  const float* Sr = sS[wv];
  const float* Fr = sF[wv];
#pragma unroll
  for (int kk = 0; kk < 4; kk++) {
    int k = lane + kk * 64;
    float a = 0.f;
    if (k < D) {
      const int b = rsK[k], e = rsK[k + 1];
      for (int t = b; t < e; t++) {
        int2 tr = trip[t];
        a += __int_as_float(tr.y) * Sr[tr.x & 0xFFFF] * Fr[tr.x >> 16];
      }
    }
    agg[(size_t)n * DP + k] = __float2bfloat16(a);  // k in [D,DP) -> 0 pad
  }
}

// ---------------------------------------------------------------------------
// Residual + LayerNorm, wave-per-node (no LDS, butterfly shfl reductions)
// ---------------------------------------------------------------------------
__global__ __launch_bounds__(256) void ln_kernel(
    const float* __restrict__ x0, const float* __restrict__ h2,
    const float* __restrict__ gamma, const float* __restrict__ beta,
    float* __restrict__ out) {
  const int tid = threadIdx.x;
  const int wv = tid >> 6;
  const int lane = tid & 63;
  const int n = blockIdx.x * 4 + wv;

  float4 x = make_float4(0.f, 0.f, 0.f, 0.f);
  if (lane < 62) {
    float4 f = *(const float4*)(x0 + (size_t)n * D + lane * 4);
    float4 h = *(const float4*)(h2 + (size_t)n * DP + lane * 4);
    x = make_float4(f.x + h.x, f.y + h.y, f.z + h.z, f.w + h.w);
  }
  float s = x.x + x.y + x.z + x.w;
#pragma unroll
  for (int o = 32; o > 0; o >>= 1) s += __shfl_xor(s, o);
  const float mu = s * (1.f / (float)D);
  float4 xc = make_float4(x.x - mu, x.y - mu, x.z - mu, x.w - mu);
  float v = 0.f;
  if (lane < 62) v = xc.x * xc.x + xc.y * xc.y + xc.z * xc.z + xc.w * xc.w;
#pragma unroll
  for (int o = 32; o > 0; o >>= 1) v += __shfl_xor(v, o);
  const float rstd = rsqrtf(v * (1.f / (float)D) + LN_EPS);
  if (lane < 62) {
    float4 g = *(const float4*)(gamma + lane * 4);
    float4 b = *(const float4*)(beta + lane * 4);
    float4 o;
    o.x = xc.x * rstd * g.x + b.x;
    o.y = xc.y * rstd * g.y + b.y;
    o.z = xc.z * rstd * g.z + b.z;
    o.w = xc.w * rstd * g.w + b.w;
    *(float4*)(out + (size_t)n * D + lane * 4) = o;
  }
}

// ---------------------------------------------------------------------------
extern "C" void kernel_launch(void* const* d_in, const int* in_sizes, int n_in,
                              void* d_out, int out_size, void* d_ws, size_t ws_size,
                              hipStream_t stream) {
  const float* features = (const float*)d_in[0];
  const int*   ei       = (const int*)d_in[1];
  const float* W_msg    = (const float*)d_in[2];
  const float* W1       = (const float*)d_in[3];
  const float* b1       = (const float*)d_in[4];
  const float* W2       = (const float*)d_in[5];
  const float* b2       = (const float*)d_in[6];
  const float* gamma    = (const float*)d_in[7];
  const float* beta     = (const float*)d_in[8];
  const int*   Iv       = (const int*)d_in[9];
  const int*   Jv       = (const int*)d_in[10];
  const int*   Kv       = (const int*)d_in[11];
  const float* Cv       = (const float*)d_in[12];
  float* out = (float*)d_out;

  char* cur = (char*)d_ws;
  auto alloc = [&](size_t bytes) {
    char* p = cur;
    cur += (bytes + 255) & ~(size_t)255;
    return p;
  };
  __hip_bfloat16* featB = (__hip_bfloat16*)alloc((size_t)N_NODES * DP * 2);  // 5.12 MB
  __hip_bfloat16* WmB   = (__hip_bfloat16*)alloc((size_t)DP * DP * 2);
  __hip_bfloat16* W1B   = (__hip_bfloat16*)alloc((size_t)HDIM * DP * 2);
  __hip_bfloat16* W2B   = (__hip_bfloat16*)alloc((size_t)DP * HDIM * 2);
  unsigned short* G     = (unsigned short*)alloc((size_t)N_NODES * DP * 2);  // 5.12 MB
  float*          S     = (float*)alloc((size_t)N_NODES * DP * 4);           // 10.24 MB
  __hip_bfloat16* aggB  = (__hip_bfloat16*)alloc((size_t)N_NODES * DP * 2);  // 5.12 MB
  unsigned short* H1B   = (unsigned short*)alloc((size_t)N_NODES * HDIM * 2);// 10.24 MB
  float*          H2    = S;  // alias: S dead once bracket has run
  int*  rsK  = (int*)alloc((D + 1) * 4);
  int2* trip = (int2*)alloc(NNZ * 8);
  int*  deg  = (int*)alloc(N_NODES * 4);
  int*  rs   = (int*)alloc((N_NODES + 1) * 4);
  int*  woff = (int*)alloc(N_NODES * 4);
  int*  esrc = (int*)alloc(N_EDGES * 4);

  dim3 blk(256);

  // 1) prep: feature+weight casts + deg zero + triple CSR
  prep_kernel<<<PREP_BLOCKS, blk, 0, stream>>>(
      features, W_msg, W1, W2, featB, WmB, W1B, W2B, deg,
      Iv, Jv, Kv, Cv, rsK, trip);
  // 2) edge CSR by target
  hist_tgt<<<(N_EDGES + 255) / 256, blk, 0, stream>>>(ei, deg);
  scan_deg<<<1, blk, 0, stream>>>(deg, rs, woff);
  place_edges<<<(N_EDGES + 255) / 256, blk, 0, stream>>>(ei, woff, esrc);
  // 3) G[n] = sum featB[src]  (bf16 gather, 16B/lane, 2 rows/wave)
  gather_G<<<N_NODES / 4, blk, 0, stream>>>(
      (const unsigned short*)featB, rs, esrc, G);
  // 4) S = G @ Wm^T  (f32 out)
  gemm_bf16<3><<<dim3(DP / 64, (N_NODES + 127) / 128), blk, 0, stream>>>(
      G, (const unsigned short*)WmB, nullptr, S, N_NODES, DP, DP, DP, DP, DP);
  // 5) agg = bracket(S, features)
  bracket_kernel<<<N_NODES / 4, blk, 0, stream>>>(S, features, rsK, trip, aggB);
  // 6) H1 = silu(agg @ W1^T + b1)
  gemm_bf16<1><<<dim3(HDIM / 64, (N_NODES + 127) / 128), blk, 0, stream>>>(
      (const unsigned short*)aggB, (const unsigned short*)W1B, b1, H1B,
      N_NODES, HDIM, DP, DP, DP, HDIM);
  // 7) H2 = H1 @ W2^T + b2  (H2 aliases S)
  gemm_bf16<2><<<dim3(DP / 64, (N_NODES + 127) / 128), blk, 0, stream>>>(
      H1B, (const unsigned short*)W2B, b2, H2, N_NODES, DP, HDIM, HDIM, HDIM, DP);
  // 8) out = LN(features + H2)
  ln_kernel<<<N_NODES / 4, blk, 0, stream>>>(features, H2, gamma, beta, out);
}

// Round 8
// 235.690 us; speedup vs baseline: 1.0755x; 1.0386x over previous
//
#include <hip/hip_runtime.h>
#include <hip/hip_bf16.h>

#define N_NODES 10000
#define N_EDGES 100000
#define D 248
#define DP 256      // padded D (K/N padding for MFMA tiles)
#define HDIM 512
#define NNZ 2480
#define LN_EPS 1e-5f

typedef __attribute__((ext_vector_type(8))) short bf16x8_t;  // 8 bf16 = 4 VGPRs
typedef __attribute__((ext_vector_type(4))) float f32x4_t;   // MFMA accum

__device__ __forceinline__ float bf2f(unsigned short u) {
  unsigned int x = ((unsigned int)u) << 16;
  return __builtin_bit_cast(float, x);
}
__device__ __forceinline__ unsigned short f2bf(float f) {
  return __builtin_bit_cast(unsigned short, __float2bfloat16(f));
}
// unpack packed 2xbf16 word: lo = bits<<16, hi = bits&0xFFFF0000
__device__ __forceinline__ float bflo(unsigned int w) {
  return __builtin_bit_cast(float, w << 16);
}
__device__ __forceinline__ float bfhi(unsigned int w) {
  return __builtin_bit_cast(float, w & 0xFFFF0000u);
}

// async global->LDS, 16B per lane. LDS dest = uniform base + lane*16.
__device__ __forceinline__ void gload_lds16(const unsigned short* gp,
                                            unsigned short* lds_base) {
  __builtin_amdgcn_global_load_lds(
      (const __attribute__((address_space(1))) void*)gp,
      (__attribute__((address_space(3))) void*)lds_base, 16, 0, 0);
}

// ---------------------------------------------------------------------------
// Fused prep, decoded by blockIdx.x:
//   [0, N)             cast features (N,D) -> featB (N,DP) bf16
//   [N, N+DP)          cast W_msg  -> WmB (DP,DP)
//   [N+DP, N+DP+H)     cast W1     -> W1B (H,DP)
//   [.., +DP)          cast W2     -> W2B (DP,H)
//   [.., +40)          deg[i] = 0
//   last               CSR of triples by K (packed int2 {J<<16|I, C})
// ---------------------------------------------------------------------------
#define CAST_BLOCKS (N_NODES + DP + HDIM + DP)
#define ZERO_BLOCKS 40
#define PREP_BLOCKS (CAST_BLOCKS + ZERO_BLOCKS + 1)

__device__ __forceinline__ void cast_row(const float* src, __hip_bfloat16* dst,
                                         int r, int sr, int sc, int dc) {
  for (int c = threadIdx.x; c < dc; c += 256) {
    float v = (r < sr && c < sc) ? src[(size_t)r * sc + c] : 0.f;
    dst[(size_t)r * dc + c] = __float2bfloat16(v);
  }
}

__global__ __launch_bounds__(256) void prep_kernel(
    const float* __restrict__ features, const float* __restrict__ W_msg,
    const float* __restrict__ W1, const float* __restrict__ W2,
    __hip_bfloat16* __restrict__ featB, __hip_bfloat16* __restrict__ WmB,
    __hip_bfloat16* __restrict__ W1B, __hip_bfloat16* __restrict__ W2B,
    int* __restrict__ deg,
    const int* __restrict__ Iv, const int* __restrict__ Jv,
    const int* __restrict__ Kv, const float* __restrict__ Cv,
    int* __restrict__ rsK, int2* __restrict__ trip) {
  const int b = blockIdx.x;
  if (b < N_NODES) {
    cast_row(features, featB, b, N_NODES, D, DP);
  } else if (b < N_NODES + DP) {
    cast_row(W_msg, WmB, b - N_NODES, D, D, DP);
  } else if (b < N_NODES + DP + HDIM) {
    cast_row(W1, W1B, b - N_NODES - DP, HDIM, D, DP);
  } else if (b < CAST_BLOCKS) {
    cast_row(W2, W2B, b - N_NODES - DP - HDIM, D, HDIM, HDIM);
  } else if (b < CAST_BLOCKS + ZERO_BLOCKS) {
    int i = (b - CAST_BLOCKS) * 256 + threadIdx.x;
    if (i < N_NODES) deg[i] = 0;
  } else {
    __shared__ int cnt[D];
    __shared__ int off[D];
    const int tid = threadIdx.x;
    for (int k = tid; k < D; k += 256) cnt[k] = 0;
    __syncthreads();
    for (int t = tid; t < NNZ; t += 256) atomicAdd(&cnt[Kv[t]], 1);
    __syncthreads();
    if (tid == 0) {
      int run = 0;
      for (int k = 0; k < D; k++) { off[k] = run; rsK[k] = run; run += cnt[k]; }
      rsK[D] = run;
    }
    __syncthreads();
    for (int t = tid; t < NNZ; t += 256) {
      int pos = atomicAdd(&off[Kv[t]], 1);
      trip[pos] = make_int2((Jv[t] << 16) | Iv[t], __float_as_int(Cv[t]));
    }
  }
}

// ---------------------------------------------------------------------------
// Edge CSR-by-target: histogram -> scan -> placement
// ---------------------------------------------------------------------------
__global__ __launch_bounds__(256) void hist_tgt(
    const int* __restrict__ ei, int* __restrict__ deg) {
  int e = blockIdx.x * 256 + threadIdx.x;
  if (e < N_EDGES) atomicAdd(&deg[ei[N_EDGES + e]], 1);
}

__global__ __launch_bounds__(256) void scan_deg(
    const int* __restrict__ deg, int* __restrict__ rs, int* __restrict__ woff) {
  __shared__ int part[256];
  const int t = threadIdx.x;
  const int base = t * 40;  // 256*40 = 10240 >= 10000
  int sum = 0;
  for (int i = 0; i < 40; i++) {
    int idx = base + i;
    if (idx < N_NODES) sum += deg[idx];
  }
  part[t] = sum;
  __syncthreads();
  if (t == 0) {
    int run = 0;
    for (int i = 0; i < 256; i++) { int tmp = part[i]; part[i] = run; run += tmp; }
    rs[N_NODES] = run;
  }
  __syncthreads();
  int run = part[t];
  for (int i = 0; i < 40; i++) {
    int idx = base + i;
    if (idx < N_NODES) { rs[idx] = run; woff[idx] = run; run += deg[idx]; }
  }
}

__global__ __launch_bounds__(256) void place_edges(
    const int* __restrict__ ei, int* __restrict__ woff, int* __restrict__ esrc) {
  int e = blockIdx.x * 256 + threadIdx.x;
  if (e < N_EDGES) {
    int pos = atomicAdd(&woff[ei[N_EDGES + e]], 1);
    esrc[pos] = ei[e];
  }
}

// ---------------------------------------------------------------------------
// Gather bf16 rows: G[n] = sum_{e: tgt=n} featB[src(e)], bf16 (N,DP) out.
// Wave per node; two 32-lane halves interleave over the edge list with
// 16B/lane uint4 loads; halves combined via shfl_xor(32).
// ---------------------------------------------------------------------------
__global__ __launch_bounds__(256) void gather_G(
    const unsigned short* __restrict__ FB, const int* __restrict__ rs,
    const int* __restrict__ esrc, unsigned short* __restrict__ G) {
  const int tid = threadIdx.x;
  const int wv = tid >> 6;
  const int lane = tid & 63;
  const int half = lane >> 5;   // 0 or 1
  const int c = lane & 31;      // 16B chunk id
  const int n = blockIdx.x * 4 + wv;  // grid 2500, exact

  const int beg = rs[n];
  const int deg = rs[n + 1] - beg;
  int eid = (lane < deg) ? esrc[beg + lane] : 0;

  float a[8] = {0.f, 0.f, 0.f, 0.f, 0.f, 0.f, 0.f, 0.f};
  const unsigned short* FBc = FB + (size_t)c * 8;
  int j = half;
  for (; j + 2 < deg && j < 64; j += 2) {
    int s = __shfl(eid, j);
    uint4 u = *(const uint4*)(FBc + (size_t)s * DP);
    a[0] += bflo(u.x); a[1] += bfhi(u.x);
    a[2] += bflo(u.y); a[3] += bfhi(u.y);
    a[4] += bflo(u.z); a[5] += bfhi(u.z);
    a[6] += bflo(u.w); a[7] += bfhi(u.w);
  }
  for (; j < deg; j += 2) {
    int s = (j < 64) ? __shfl(eid, j) : esrc[beg + j];
    uint4 u = *(const uint4*)(FBc + (size_t)s * DP);
    a[0] += bflo(u.x); a[1] += bfhi(u.x);
    a[2] += bflo(u.y); a[3] += bfhi(u.y);
    a[4] += bflo(u.z); a[5] += bfhi(u.z);
    a[6] += bflo(u.w); a[7] += bfhi(u.w);
  }
#pragma unroll
  for (int i = 0; i < 8; i++) a[i] += __shfl_xor(a[i], 32);

  if (half == 0) {
    uint4 o;
    o.x = (unsigned)f2bf(a[0]) | ((unsigned)f2bf(a[1]) << 16);
    o.y = (unsigned)f2bf(a[2]) | ((unsigned)f2bf(a[3]) << 16);
    o.z = (unsigned)f2bf(a[4]) | ((unsigned)f2bf(a[5]) << 16);
    o.w = (unsigned)f2bf(a[6]) | ((unsigned)f2bf(a[7]) << 16);
    *(uint4*)(G + (size_t)n * DP + c * 8) = o;
  }
}

// ---------------------------------------------------------------------------
// bf16 GEMM-NT via MFMA 16x16x32, async global_load_lds staging (m97-style):
// C = A @ B^T (+bias)(+silu). Tile 128x64x64, 4 waves 2x2, contiguous LDS
// (no swizzle -- global_load_lds requires dest = uniform base + lane*16).
// A-tile rows >= M load garbage (in-ws) -- harmless, those C rows are skipped.
// EPI: 0 = bf16 out; 1 = +bias +silu, bf16 out; 2 = +bias(n<D), f32 out;
//      3 = plain f32 out.
// ---------------------------------------------------------------------------
template <int EPI>
__global__ __launch_bounds__(256) void gemm_bf16(
    const unsigned short* __restrict__ A, const unsigned short* __restrict__ B,
    const float* __restrict__ bias, void* __restrict__ Cout,
    int M, int Nn, int K, int lda, int ldb, int ldc) {
  constexpr int BM = 128;
  __shared__ unsigned short As[BM * 64];  // 16 KB, row-major [row][64]
  __shared__ unsigned short Bs[64 * 64];  // 8 KB
  const int tid = threadIdx.x;
  const int wave = tid >> 6;
  const int lane = tid & 63;
  const int wm = wave >> 1;
  const int wn = wave & 1;
  const int ml = lane & 15;
  const int q = lane >> 4;
  const int m0 = blockIdx.y * BM;
  const int n0 = blockIdx.x * 64;

  // per-lane source row/granule for staging (8 rows, 8 granules per inst)
  const int srow = lane >> 3;   // 0..7
  const int sg = lane & 7;      // 0..7

  f32x4_t acc[4][2];
#pragma unroll
  for (int i = 0; i < 4; i++)
#pragma unroll
    for (int j = 0; j < 2; j++) acc[i][j] = (f32x4_t)0.f;

  for (int k0 = 0; k0 < K; k0 += 64) {
    // A: 16 insts total (4/wave), each moves 8 rows x 64 cols = 1 KB
#pragma unroll
    for (int i = 0; i < 4; i++) {
      int t = wave * 4 + i;
      const unsigned short* gp =
          A + (size_t)(m0 + t * 8 + srow) * lda + k0 + sg * 8;
      gload_lds16(gp, As + t * 512);
    }
    // B: 8 insts total (2/wave)
#pragma unroll
    for (int i = 0; i < 2; i++) {
      int t = wave * 2 + i;
      const unsigned short* gp =
          B + (size_t)(n0 + t * 8 + srow) * ldb + k0 + sg * 8;
      gload_lds16(gp, Bs + t * 512);
    }
    __syncthreads();  // compiler drains vmcnt before barrier
#pragma unroll
    for (int kk = 0; kk < 2; kk++) {
      bf16x8_t a[4], b[2];
#pragma unroll
      for (int im = 0; im < 4; im++) {
        int row = wm * 64 + im * 16 + ml;
        a[im] = *(const bf16x8_t*)(As + row * 64 + (kk * 4 + q) * 8);
      }
#pragma unroll
      for (int jn = 0; jn < 2; jn++) {
        int row = wn * 32 + jn * 16 + ml;
        b[jn] = *(const bf16x8_t*)(Bs + row * 64 + (kk * 4 + q) * 8);
      }
#pragma unroll
      for (int im = 0; im < 4; im++)
#pragma unroll
        for (int jn = 0; jn < 2; jn++)
          acc[im][jn] = __builtin_amdgcn_mfma_f32_16x16x32_bf16(
              a[im], b[jn], acc[im][jn], 0, 0, 0);
    }
    __syncthreads();
  }

  // D[m][n]: n = lane&15, m = quad*4 + reg  [verified m89/m91]
#pragma unroll
  for (int im = 0; im < 4; im++) {
#pragma unroll
    for (int jn = 0; jn < 2; jn++) {
      int gn = n0 + wn * 32 + jn * 16 + ml;
#pragma unroll
      for (int reg = 0; reg < 4; reg++) {
        int gm = m0 + wm * 64 + im * 16 + q * 4 + reg;
        if (gm >= M) continue;
        float v = acc[im][jn][reg];
        if (EPI == 1) {
          v += bias[gn];
          v = v / (1.f + __expf(-v));
          ((__hip_bfloat16*)Cout)[(size_t)gm * ldc + gn] = __float2bfloat16(v);
        } else if (EPI == 2) {
          v += (gn < D) ? bias[gn] : 0.f;
          ((float*)Cout)[(size_t)gm * ldc + gn] = v;
        } else if (EPI == 3) {
          ((float*)Cout)[(size_t)gm * ldc + gn] = v;
        } else {
          ((__hip_bfloat16*)Cout)[(size_t)gm * ldc + gn] = __float2bfloat16(v);
        }
      }
    }
  }
}

// ---------------------------------------------------------------------------
// Per-node bracket (S and F staged in LDS; wave-per-node, 4/block):
//   agg[n][k] = sum_{t in rowK(k)} C_t * S[n][I_t] * F[n][J_t]
// ---------------------------------------------------------------------------
__global__ __launch_bounds__(256) void bracket_kernel(
    const float* __restrict__ S, const float* __restrict__ F,
    const int* __restrict__ rsK, const int2* __restrict__ trip,
    __hip_bfloat16* __restrict__ agg) {
  __shared__ float sS[4][DP];
  __shared__ float sF[4][DP];
  const int tid = threadIdx.x;
  const int wv = tid >> 6;
  const int lane = tid & 63;
  const int n = blockIdx.x * 4 + wv;

  ((float4*)sS[wv])[lane] = ((const float4*)(S + (size_t)n * DP))[lane];
  if (lane < 62) ((float4*)sF[wv])[lane] = ((const float4*)(F + (size_t)n * D))[lane];
  __syncthreads();

  const float* Sr = sS[wv];
  const float* Fr = sF[wv];
#pragma unroll
  for (int kk = 0; kk < 4; kk++) {
    int k = lane + kk * 64;
    float a = 0.f;
    if (k < D) {
      const int b = rsK[k], e = rsK[k + 1];
      for (int t = b; t < e; t++) {
        int2 tr = trip[t];
        a += __int_as_float(tr.y) * Sr[tr.x & 0xFFFF] * Fr[tr.x >> 16];
      }
    }
    agg[(size_t)n * DP + k] = __float2bfloat16(a);  // k in [D,DP) -> 0 pad
  }
}

// ---------------------------------------------------------------------------
// Residual + LayerNorm, wave-per-node (no LDS, butterfly shfl reductions)
// ---------------------------------------------------------------------------
__global__ __launch_bounds__(256) void ln_kernel(
    const float* __restrict__ x0, const float* __restrict__ h2,
    const float* __restrict__ gamma, const float* __restrict__ beta,
    float* __restrict__ out) {
  const int tid = threadIdx.x;
  const int wv = tid >> 6;
  const int lane = tid & 63;
  const int n = blockIdx.x * 4 + wv;

  float4 x = make_float4(0.f, 0.f, 0.f, 0.f);
  if (lane < 62) {
    float4 f = *(const float4*)(x0 + (size_t)n * D + lane * 4);
    float4 h = *(const float4*)(h2 + (size_t)n * DP + lane * 4);
    x = make_float4(f.x + h.x, f.y + h.y, f.z + h.z, f.w + h.w);
  }
  float s = x.x + x.y + x.z + x.w;
#pragma unroll
  for (int o = 32; o > 0; o >>= 1) s += __shfl_xor(s, o);
  const float mu = s * (1.f / (float)D);
  float4 xc = make_float4(x.x - mu, x.y - mu, x.z - mu, x.w - mu);
  float v = 0.f;
  if (lane < 62) v = xc.x * xc.x + xc.y * xc.y + xc.z * xc.z + xc.w * xc.w;
#pragma unroll
  for (int o = 32; o > 0; o >>= 1) v += __shfl_xor(v, o);
  const float rstd = rsqrtf(v * (1.f / (float)D) + LN_EPS);
  if (lane < 62) {
    float4 g = *(const float4*)(gamma + lane * 4);
    float4 b = *(const float4*)(beta + lane * 4);
    float4 o;
    o.x = xc.x * rstd * g.x + b.x;
    o.y = xc.y * rstd * g.y + b.y;
    o.z = xc.z * rstd * g.z + b.z;
    o.w = xc.w * rstd * g.w + b.w;
    *(float4*)(out + (size_t)n * D + lane * 4) = o;
  }
}

// ---------------------------------------------------------------------------
extern "C" void kernel_launch(void* const* d_in, const int* in_sizes, int n_in,
                              void* d_out, int out_size, void* d_ws, size_t ws_size,
                              hipStream_t stream) {
  const float* features = (const float*)d_in[0];
  const int*   ei       = (const int*)d_in[1];
  const float* W_msg    = (const float*)d_in[2];
  const float* W1       = (const float*)d_in[3];
  const float* b1       = (const float*)d_in[4];
  const float* W2       = (const float*)d_in[5];
  const float* b2       = (const float*)d_in[6];
  const float* gamma    = (const float*)d_in[7];
  const float* beta     = (const float*)d_in[8];
  const int*   Iv       = (const int*)d_in[9];
  const int*   Jv       = (const int*)d_in[10];
  const int*   Kv       = (const int*)d_in[11];
  const float* Cv       = (const float*)d_in[12];
  float* out = (float*)d_out;

  char* cur = (char*)d_ws;
  auto alloc = [&](size_t bytes) {
    char* p = cur;
    cur += (bytes + 255) & ~(size_t)255;
    return p;
  };
  __hip_bfloat16* featB = (__hip_bfloat16*)alloc((size_t)N_NODES * DP * 2);  // 5.12 MB
  __hip_bfloat16* WmB   = (__hip_bfloat16*)alloc((size_t)DP * DP * 2);
  __hip_bfloat16* W1B   = (__hip_bfloat16*)alloc((size_t)HDIM * DP * 2);
  __hip_bfloat16* W2B   = (__hip_bfloat16*)alloc((size_t)DP * HDIM * 2);
  unsigned short* G     = (unsigned short*)alloc((size_t)N_NODES * DP * 2);  // 5.12 MB
  float*          S     = (float*)alloc((size_t)N_NODES * DP * 4);           // 10.24 MB
  __hip_bfloat16* aggB  = (__hip_bfloat16*)alloc((size_t)N_NODES * DP * 2);  // 5.12 MB
  unsigned short* H1B   = (unsigned short*)alloc((size_t)N_NODES * HDIM * 2);// 10.24 MB
  float*          H2    = S;  // alias: S dead once bracket has run
  int*  rsK  = (int*)alloc((D + 1) * 4);
  int2* trip = (int2*)alloc(NNZ * 8);
  int*  deg  = (int*)alloc(N_NODES * 4);
  int*  rs   = (int*)alloc((N_NODES + 1) * 4);
  int*  woff = (int*)alloc(N_NODES * 4);
  int*  esrc = (int*)alloc(N_EDGES * 4);

  dim3 blk(256);

  // 1) prep: feature+weight casts + deg zero + triple CSR
  prep_kernel<<<PREP_BLOCKS, blk, 0, stream>>>(
      features, W_msg, W1, W2, featB, WmB, W1B, W2B, deg,
      Iv, Jv, Kv, Cv, rsK, trip);
  // 2) edge CSR by target
  hist_tgt<<<(N_EDGES + 255) / 256, blk, 0, stream>>>(ei, deg);
  scan_deg<<<1, blk, 0, stream>>>(deg, rs, woff);
  place_edges<<<(N_EDGES + 255) / 256, blk, 0, stream>>>(ei, woff, esrc);
  // 3) G[n] = sum featB[src]  (bf16 gather, 16B/lane, 2 rows/wave)
  gather_G<<<N_NODES / 4, blk, 0, stream>>>(
      (const unsigned short*)featB, rs, esrc, G);
  // 4) S = G @ Wm^T  (f32 out)
  gemm_bf16<3><<<dim3(DP / 64, (N_NODES + 127) / 128), blk, 0, stream>>>(
      G, (const unsigned short*)WmB, nullptr, S, N_NODES, DP, DP, DP, DP, DP);
  // 5) agg = bracket(S, features)
  bracket_kernel<<<N_NODES / 4, blk, 0, stream>>>(S, features, rsK, trip, aggB);
  // 6) H1 = silu(agg @ W1^T + b1)
  gemm_bf16<1><<<dim3(HDIM / 64, (N_NODES + 127) / 128), blk, 0, stream>>>(
      (const unsigned short*)aggB, (const unsigned short*)W1B, b1, H1B,
      N_NODES, HDIM, DP, DP, DP, HDIM);
  // 7) H2 = H1 @ W2^T + b2  (H2 aliases S)
  gemm_bf16<2><<<dim3(DP / 64, (N_NODES + 127) / 128), blk, 0, stream>>>(
      H1B, (const unsigned short*)W2B, b2, H2, N_NODES, DP, HDIM, HDIM, HDIM, DP);
  // 8) out = LN(features + H2)
  ln_kernel<<<N_NODES / 4, blk, 0, stream>>>(features, H2, gamma, beta, out);
}